// Round 4
// baseline (743.596 us; speedup 1.0000x reference)
//
#include <hip/hip_runtime.h>
#include <math.h>

#define EPSBN 1e-5f

// ---------------------------------------------------------------------------
// Kernel 1: fused time-average + lin2 + relu + BN3, one block per graph.
// grid = 256 blocks == 256 CUs, perfectly balanced, HBM-bound (389 MB x read).
// Per block: stream the graph's 19x20000 x-slice in 50 k-chunks (16 h1-cols =
// 400 x-floats/row per chunk), double-buffered LDS; reduce 25->1 into At[19x16];
// thread t owns output column n=t, accumulates acc[19] over K=800.
// GEMM compute (~15 us chip-wide) hides entirely under the 62 us HBM stream;
// h1 never exists in global memory (saves its write + re-read + one launch).
// ---------------------------------------------------------------------------
__global__ __launch_bounds__(256)
void front_fused(const float* __restrict__ x,
                 const float* __restrict__ w2, const float* __restrict__ b2,
                 const float* __restrict__ g3, const float* __restrict__ bb3,
                 const float* __restrict__ rm3, const float* __restrict__ rv3,
                 float* __restrict__ h2)
{
    __shared__ __align__(16) float sx[2][19 * 400];   // 60.8 KB x-chunk dbuf
    __shared__ __align__(16) float sw[2][16 * 264];   // 33.8 KB w2-chunk dbuf (k-major, padded)
    __shared__ __align__(16) float At[20 * 16];       //  1.3 KB reduced A tile
    __shared__ float s3s[19], s3h[19];

    const int t = threadIdx.x;
    const int g = blockIdx.x;

    // ---- chunk-invariant loader mappings ----
    // x: 1900 float4 per chunk = 19 rows x 100 float4. Slot i covers f=t+256*i.
    // Slots 0..6 always valid; slot 7 valid iff t < 108 (1792+108 = 1900).
    int xoff[8];            // LDS float offset: r*400 + c4*4
    size_t xbase[8];        // global float offset: node_row*20000 + c4*4
#pragma unroll
    for (int i = 0; i < 8; ++i) {
        const int f = t + 256 * i;
        int r = f / 100;
        const int c4 = f - r * 100;
        if (r > 18) r = 18;            // slot 7 unused lanes: keep addr in-range
        xoff[i] = r * 400 + c4 * 4;
        xbase[i] = (size_t)(g * 19 + r) * 20000 + (size_t)c4 * 4;
    }
    const bool x7ok = (t < 108);
    // w2: 1024 float4 per chunk. Slot i: n = (t>>2)+64*i, k-quad q = t&3.
    const int wq = t & 3;
    int wn[4];
#pragma unroll
    for (int i = 0; i < 4; ++i) wn[i] = (t >> 2) + 64 * i;

    if (t < 19) {                                    // BN3 affine fold
        const float sc = g3[t] * (1.0f / sqrtf(rv3[t] + EPSBN));
        s3s[t] = sc; s3h[t] = bb3[t] - rm3[t] * sc;
    }

    float4 xv[8], wv[4];
    float acc[19];
#pragma unroll
    for (int r = 0; r < 19; ++r) acc[r] = 0.f;

    // ---- prologue: chunk 0 -> regs -> LDS buf 0 ----
#pragma unroll
    for (int i = 0; i < 7; ++i) xv[i] = *(const float4*)(x + xbase[i]);
    if (x7ok) xv[7] = *(const float4*)(x + xbase[7]);
#pragma unroll
    for (int i = 0; i < 4; ++i) wv[i] = *(const float4*)(w2 + (size_t)wn[i] * 800 + wq * 4);
#pragma unroll
    for (int i = 0; i < 7; ++i) *(float4*)&sx[0][xoff[i]] = xv[i];
    if (x7ok) *(float4*)&sx[0][xoff[7]] = xv[7];
#pragma unroll
    for (int i = 0; i < 4; ++i) {
        sw[0][(wq * 4 + 0) * 264 + wn[i]] = wv[i].x;
        sw[0][(wq * 4 + 1) * 264 + wn[i]] = wv[i].y;
        sw[0][(wq * 4 + 2) * 264 + wn[i]] = wv[i].z;
        sw[0][(wq * 4 + 3) * 264 + wn[i]] = wv[i].w;
    }
    __syncthreads();

    int cur = 0;
    for (int kc = 0; kc < 50; ++kc) {
        // issue next chunk's global loads (latency hides under reduce+matmul)
        if (kc < 49) {
            const size_t xk = (size_t)(kc + 1) * 400;
            const size_t wk = (size_t)(kc + 1) * 16;
#pragma unroll
            for (int i = 0; i < 7; ++i) xv[i] = *(const float4*)(x + xbase[i] + xk);
            if (x7ok) xv[7] = *(const float4*)(x + xbase[7] + xk);
#pragma unroll
            for (int i = 0; i < 4; ++i)
                wv[i] = *(const float4*)(w2 + (size_t)wn[i] * 800 + wk + wq * 4);
        }

        // reduce 25->1:  At[r][kk] = mean(sx[cur][r][kk*25 .. +24])
        for (int idx = t; idx < 304; idx += 256) {
            const int r = idx >> 4, kk = idx & 15;
            const float* p = &sx[cur][r * 400 + kk * 25];
            float s = 0.f;
#pragma unroll
            for (int j = 0; j < 25; ++j) s += p[j];
            At[r * 16 + kk] = s * (1.0f / 25.0f);
        }
        __syncthreads();                      // At ready

        // matmul: acc[r] += At[r][kk] * w2[n=t][kc*16+kk]
#pragma unroll
        for (int k4 = 0; k4 < 4; ++k4) {
            const float w0 = sw[cur][(k4 * 4 + 0) * 264 + t];
            const float w1 = sw[cur][(k4 * 4 + 1) * 264 + t];
            const float w2v = sw[cur][(k4 * 4 + 2) * 264 + t];
            const float w3v = sw[cur][(k4 * 4 + 3) * 264 + t];
#pragma unroll
            for (int r = 0; r < 19; ++r) {
                const float4 a = *(const float4*)&At[r * 16 + k4 * 4];
                acc[r] += a.x * w0 + a.y * w1 + a.z * w2v + a.w * w3v;
            }
        }

        // write next chunk regs -> LDS (other buffer)
        if (kc < 49) {
            const int nxt = cur ^ 1;
#pragma unroll
            for (int i = 0; i < 7; ++i) *(float4*)&sx[nxt][xoff[i]] = xv[i];
            if (x7ok) *(float4*)&sx[nxt][xoff[7]] = xv[7];
#pragma unroll
            for (int i = 0; i < 4; ++i) {
                sw[nxt][(wq * 4 + 0) * 264 + wn[i]] = wv[i].x;
                sw[nxt][(wq * 4 + 1) * 264 + wn[i]] = wv[i].y;
                sw[nxt][(wq * 4 + 2) * 264 + wn[i]] = wv[i].z;
                sw[nxt][(wq * 4 + 3) * 264 + wn[i]] = wv[i].w;
            }
        }
        __syncthreads();                      // buffers swapped safely
        cur ^= 1;
    }

    // epilogue: bias + relu + BN3 (per-electrode = per-row within graph)
    const float bn = b2[t];
#pragma unroll
    for (int r = 0; r < 19; ++r) {
        const float v = fmaxf(acc[r] + bn, 0.f) * s3s[r] + s3h[r];
        h2[((size_t)g * 19 + r) * 256 + t] = v;
    }
}

// ---------------------------------------------------------------------------
// Kernel 2: fused lin3+BN4 then lin4+BN5 for a 32-row stripe. (R1 version,
// known good: 152 blocks, 2 blocks/CU, conflict-fixed LDS strides.)
// ---------------------------------------------------------------------------
__global__ __launch_bounds__(256)
void gemm23_fused(const float* __restrict__ h2,
                  const float* __restrict__ w3, const float* __restrict__ b3,
                  const float* __restrict__ g4, const float* __restrict__ bb4,
                  const float* __restrict__ rm4, const float* __restrict__ rv4,
                  const float* __restrict__ w4, const float* __restrict__ b4,
                  const float* __restrict__ g5, const float* __restrict__ bb5,
                  const float* __restrict__ rm5, const float* __restrict__ rv5,
                  float* __restrict__ h4out)
{
    __shared__ __align__(16) float As[32][36];
    __shared__ __align__(16) float Ws[32][132];
    __shared__ __align__(16) float C1[32][132];
    __shared__ __align__(16) float W4T[128][68];

    const int t = threadIdx.x;
    const int bm = blockIdx.x * 32;

    const int tm0 = (t >> 5) * 4;
    const int tn0 = (t & 31) * 4;
    const int ar = t >> 3;
    const int ac = (t & 7) * 4;

    float acc[4][4] = {};
    const float* Ap = h2 + (size_t)(bm + ar) * 256 + ac;
    float4 areg = *(const float4*)Ap;
    float4 wreg[4];
#pragma unroll
    for (int i = 0; i < 4; ++i)
        wreg[i] = *(const float4*)(w3 + (size_t)(ar + i * 32) * 256 + ac);

    for (int k0 = 0; k0 < 256; k0 += 32) {
        __syncthreads();
        As[ac + 0][ar] = areg.x; As[ac + 1][ar] = areg.y;
        As[ac + 2][ar] = areg.z; As[ac + 3][ar] = areg.w;
#pragma unroll
        for (int i = 0; i < 4; ++i) {
            const int row = ar + i * 32;
            Ws[ac + 0][row] = wreg[i].x; Ws[ac + 1][row] = wreg[i].y;
            Ws[ac + 2][row] = wreg[i].z; Ws[ac + 3][row] = wreg[i].w;
        }
        __syncthreads();
        if (k0 + 32 < 256) {
            areg = *(const float4*)(Ap + k0 + 32);
#pragma unroll
            for (int i = 0; i < 4; ++i)
                wreg[i] = *(const float4*)(w3 + (size_t)(ar + i * 32) * 256 + ac + k0 + 32);
        }
#pragma unroll
        for (int kk = 0; kk < 32; ++kk) {
            float4 a = *(const float4*)&As[kk][tm0];
            float4 b = *(const float4*)&Ws[kk][tn0];
            acc[0][0] += a.x * b.x; acc[0][1] += a.x * b.y;
            acc[0][2] += a.x * b.z; acc[0][3] += a.x * b.w;
            acc[1][0] += a.y * b.x; acc[1][1] += a.y * b.y;
            acc[1][2] += a.y * b.z; acc[1][3] += a.y * b.w;
            acc[2][0] += a.z * b.x; acc[2][1] += a.z * b.y;
            acc[2][2] += a.z * b.z; acc[2][3] += a.z * b.w;
            acc[3][0] += a.w * b.x; acc[3][1] += a.w * b.y;
            acc[3][2] += a.w * b.z; acc[3][3] += a.w * b.w;
        }
    }

    {
        const float c0 = b3[tn0 + 0], c1 = b3[tn0 + 1];
        const float c2 = b3[tn0 + 2], c3 = b3[tn0 + 3];
#pragma unroll
        for (int i = 0; i < 4; ++i) {
            const int e = (bm + tm0 + i) % 19;
            const float scale = g4[e] * (1.0f / sqrtf(rv4[e] + EPSBN));
            const float shift = bb4[e] - rm4[e] * scale;
            float4 o;
            o.x = fmaxf(acc[i][0] + c0, 0.f) * scale + shift;
            o.y = fmaxf(acc[i][1] + c1, 0.f) * scale + shift;
            o.z = fmaxf(acc[i][2] + c2, 0.f) * scale + shift;
            o.w = fmaxf(acc[i][3] + c3, 0.f) * scale + shift;
            *(float4*)&C1[tm0 + i][tn0] = o;
        }
    }

    {
        const int ln = t & 63, wq = t >> 6;
#pragma unroll
        for (int ii = 0; ii < 8; ++ii) {
            const int c4 = wq + ii * 4;
            const float4 v = *(const float4*)(w4 + (size_t)ln * 128 + c4 * 4);
            W4T[c4 * 4 + 0][ln] = v.x;
            W4T[c4 * 4 + 1][ln] = v.y;
            W4T[c4 * 4 + 2][ln] = v.z;
            W4T[c4 * 4 + 3][ln] = v.w;
        }
    }
    __syncthreads();

    const int rm2 = (t >> 4) * 2;
    const int cn2 = (t & 15) * 4;
    float acc2[2][4] = {};
#pragma unroll 4
    for (int k = 0; k < 128; ++k) {
        const float a0 = C1[rm2 + 0][k];
        const float a1 = C1[rm2 + 1][k];
        const float4 w = *(const float4*)&W4T[k][cn2];
        acc2[0][0] += a0 * w.x; acc2[0][1] += a0 * w.y;
        acc2[0][2] += a0 * w.z; acc2[0][3] += a0 * w.w;
        acc2[1][0] += a1 * w.x; acc2[1][1] += a1 * w.y;
        acc2[1][2] += a1 * w.z; acc2[1][3] += a1 * w.w;
    }
    {
        const float c0 = b4[cn2 + 0], c1 = b4[cn2 + 1];
        const float c2 = b4[cn2 + 2], c3 = b4[cn2 + 3];
#pragma unroll
        for (int i = 0; i < 2; ++i) {
            const int row = bm + rm2 + i;
            const int e = row % 19;
            const float scale = g5[e] * (1.0f / sqrtf(rv5[e] + EPSBN));
            const float shift = bb5[e] - rm5[e] * scale;
            float4 o;
            o.x = fmaxf(acc2[i][0] + c0, 0.f) * scale + shift;
            o.y = fmaxf(acc2[i][1] + c1, 0.f) * scale + shift;
            o.z = fmaxf(acc2[i][2] + c2, 0.f) * scale + shift;
            o.w = fmaxf(acc2[i][3] + c3, 0.f) * scale + shift;
            *(float4*)(h4out + (size_t)row * 64 + cn2) = o;
        }
    }
}

// ---------------------------------------------------------------------------
// Kernel 3: fused GC1 + BN6 + GC2 + BN7 + maxpool + lin5 + 3 heads.
// One block (128 thr) per graph. (R1 version, known good.)
// ---------------------------------------------------------------------------
__global__ __launch_bounds__(128)
void graph_head_kernel(const float* __restrict__ h,
                       const int* __restrict__ ei,
                       const float* __restrict__ ew1, const float* __restrict__ ew2,
                       const float* __restrict__ wrel1, const float* __restrict__ brel1,
                       const float* __restrict__ wroot1,
                       const float* __restrict__ g6, const float* __restrict__ b6,
                       const float* __restrict__ rm6, const float* __restrict__ rv6,
                       const float* __restrict__ wrel2, const float* __restrict__ brel2,
                       const float* __restrict__ wroot2,
                       const float* __restrict__ g7, const float* __restrict__ b7,
                       const float* __restrict__ rm7, const float* __restrict__ rv7,
                       const float* __restrict__ lin5w, const float* __restrict__ lin5b,
                       const float* __restrict__ hmw, const float* __restrict__ hmb,
                       const float* __restrict__ hbw, const float* __restrict__ hbb,
                       const float* __restrict__ hdw, const float* __restrict__ hdb,
                       float* __restrict__ out, int nB, int nEdgeTot)
{
    __shared__ __align__(16) float sh[19 * 64];
    __shared__ __align__(16) float sagg[19 * 64];
    __shared__ __align__(16) float sh2[19 * 32];
    __shared__ __align__(16) float sagg2[19 * 32];
    __shared__ __align__(16) float sh3[19 * 32];
    __shared__ __align__(16) float swrel1[32 * 64];
    __shared__ __align__(16) float swroot1[32 * 64];
    __shared__ __align__(16) float swrel2[32 * 32];
    __shared__ __align__(16) float swroot2[32 * 32];
    __shared__ __align__(16) float slin5[32 * 32];
    __shared__ float sz[32], szz[32];
    __shared__ int ssrc[60], sdst[60];
    __shared__ float sew1[60], sew2[60];

    const int t = threadIdx.x;
    const int g = blockIdx.x;

    for (int i = t; i < 19 * 64; i += 128) { sh[i] = h[(size_t)g * 19 * 64 + i]; sagg[i] = 0.f; }
    for (int i = t; i < 19 * 32; i += 128) sagg2[i] = 0.f;
    for (int i = t; i < 2048; i += 128) { swrel1[i] = wrel1[i]; swroot1[i] = wroot1[i]; }
    for (int i = t; i < 1024; i += 128) { swrel2[i] = wrel2[i]; swroot2[i] = wroot2[i]; slin5[i] = lin5w[i]; }
    if (t < 60) {
        ssrc[t] = ei[g * 60 + t] - g * 19;
        sdst[t] = ei[nEdgeTot + g * 60 + t] - g * 19;
        sew1[t] = ew1[t];
        sew2[t] = ew2[t];
    }
    __syncthreads();

    if (t < 64) {
        for (int e = 0; e < 60; ++e)
            sagg[sdst[e] * 64 + t] += sew1[e] * sh[ssrc[e] * 64 + t];
    }
    __syncthreads();

    for (int idx = t; idx < 19 * 32; idx += 128) {
        const int n = idx >> 5, j = idx & 31;
        const float4* ag = (const float4*)&sagg[n * 64];
        const float4* hg = (const float4*)&sh[n * 64];
        const float4* wr = (const float4*)&swrel1[j * 64];
        const float4* wo = (const float4*)&swroot1[j * 64];
        float acc = brel1[j];
#pragma unroll
        for (int k = 0; k < 16; ++k) {
            float4 a = ag[k], w = wr[k], x = hg[k], u = wo[k];
            acc += a.x * w.x + a.y * w.y + a.z * w.z + a.w * w.w;
            acc += x.x * u.x + x.y * u.y + x.z * u.z + x.w * u.w;
        }
        float v = fmaxf(acc, 0.f);
        const float scale = g6[j] * (1.0f / sqrtf(rv6[j] + EPSBN));
        sh2[idx] = (v - rm6[j]) * scale + b6[j];
    }
    __syncthreads();

    if (t < 32) {
        for (int e = 0; e < 60; ++e)
            sagg2[sdst[e] * 32 + t] += sew2[e] * sh2[ssrc[e] * 32 + t];
    }
    __syncthreads();

    for (int idx = t; idx < 19 * 32; idx += 128) {
        const int n = idx >> 5, j = idx & 31;
        const float4* ag = (const float4*)&sagg2[n * 32];
        const float4* hg = (const float4*)&sh2[n * 32];
        const float4* wr = (const float4*)&swrel2[j * 32];
        const float4* wo = (const float4*)&swroot2[j * 32];
        float acc = brel2[j];
#pragma unroll
        for (int k = 0; k < 8; ++k) {
            float4 a = ag[k], w = wr[k], x = hg[k], u = wo[k];
            acc += a.x * w.x + a.y * w.y + a.z * w.z + a.w * w.w;
            acc += x.x * u.x + x.y * u.y + x.z * u.z + x.w * u.w;
        }
        float v = fmaxf(acc, 0.f);
        const float scale = g7[j] * (1.0f / sqrtf(rv7[j] + EPSBN));
        sh3[idx] = (v - rm7[j]) * scale + b7[j];
    }
    __syncthreads();

    if (t < 32) {
        float m = sh3[t];
        for (int n = 1; n < 19; ++n) m = fmaxf(m, sh3[n * 32 + t]);
        sz[t] = m;
    }
    __syncthreads();

    if (t < 32) {
        float acc = lin5b[t];
        const float4* zp = (const float4*)sz;
        const float4* wp = (const float4*)&slin5[t * 32];
#pragma unroll
        for (int k = 0; k < 8; ++k) {
            float4 z = zp[k], w = wp[k];
            acc += z.x * w.x + z.y * w.y + z.z * w.z + z.w * w.w;
        }
        szz[t] = fmaxf(acc, 0.f);
    }
    __syncthreads();

    if (t < 3) {
        float acc = hmb[t];
        for (int k = 0; k < 32; ++k) acc += szz[k] * hmw[t * 32 + k];
        out[g * 3 + t] = acc;
    } else if (t < 5) {
        const int j = t - 3;
        float acc = hbb[j];
        for (int k = 0; k < 32; ++k) acc += szz[k] * hbw[j * 32 + k];
        out[nB * 3 + g * 2 + j] = acc;
    } else if (t < 7) {
        const int j = t - 5;
        float acc = hdb[j];
        for (int k = 0; k < 32; ++k) acc += szz[k] * hdw[j * 32 + k];
        out[nB * 5 + g * 2 + j] = acc;
    }
}

// ---------------------------------------------------------------------------
extern "C" void kernel_launch(void* const* d_in, const int* in_sizes, int n_in,
                              void* d_out, int out_size, void* d_ws, size_t ws_size,
                              hipStream_t stream)
{
    const float* x       = (const float*)d_in[0];
    const int*   ei      = (const int*)d_in[1];
    const float* lin2_w  = (const float*)d_in[3];
    const float* lin2_b  = (const float*)d_in[4];
    const float* bn3_g   = (const float*)d_in[5];
    const float* bn3_b   = (const float*)d_in[6];
    const float* bn3_rm  = (const float*)d_in[7];
    const float* bn3_rv  = (const float*)d_in[8];
    const float* lin3_w  = (const float*)d_in[9];
    const float* lin3_b  = (const float*)d_in[10];
    const float* bn4_g   = (const float*)d_in[11];
    const float* bn4_b   = (const float*)d_in[12];
    const float* bn4_rm  = (const float*)d_in[13];
    const float* bn4_rv  = (const float*)d_in[14];
    const float* lin4_w  = (const float*)d_in[15];
    const float* lin4_b  = (const float*)d_in[16];
    const float* bn5_g   = (const float*)d_in[17];
    const float* bn5_b   = (const float*)d_in[18];
    const float* bn5_rm  = (const float*)d_in[19];
    const float* bn5_rv  = (const float*)d_in[20];
    const float* ew1     = (const float*)d_in[21];
    const float* gc1_wrel  = (const float*)d_in[22];
    const float* gc1_brel  = (const float*)d_in[23];
    const float* gc1_wroot = (const float*)d_in[24];
    const float* bn6_g   = (const float*)d_in[25];
    const float* bn6_b   = (const float*)d_in[26];
    const float* bn6_rm  = (const float*)d_in[27];
    const float* bn6_rv  = (const float*)d_in[28];
    const float* ew2     = (const float*)d_in[29];
    const float* gc2_wrel  = (const float*)d_in[30];
    const float* gc2_brel  = (const float*)d_in[31];
    const float* gc2_wroot = (const float*)d_in[32];
    const float* bn7_g   = (const float*)d_in[33];
    const float* bn7_b   = (const float*)d_in[34];
    const float* bn7_rm  = (const float*)d_in[35];
    const float* bn7_rv  = (const float*)d_in[36];
    const float* lin5_w  = (const float*)d_in[37];
    const float* lin5_b  = (const float*)d_in[38];
    const float* hm_w    = (const float*)d_in[39];
    const float* hm_b    = (const float*)d_in[40];
    const float* hb_w    = (const float*)d_in[41];
    const float* hb_b    = (const float*)d_in[42];
    const float* hd_w    = (const float*)d_in[43];
    const float* hd_b    = (const float*)d_in[44];

    const int n_nodes = in_sizes[0] / 20000;   // 4864
    const int B = n_nodes / 19;                // 256

    float* h2 = (float*)d_ws;                         // (n_nodes, 256)
    float* h4 = h2 + (size_t)n_nodes * 256;           // (n_nodes, 64)

    // 1) fused time-average + lin2 + relu + bn3 (one block per graph)
    front_fused<<<B, 256, 0, stream>>>(x, lin2_w, lin2_b,
                                       bn3_g, bn3_b, bn3_rm, bn3_rv, h2);

    // 2) fused lin3+bn4 / lin4+bn5
    gemm23_fused<<<n_nodes / 32, 256, 0, stream>>>(h2,
                                                   lin3_w, lin3_b,
                                                   bn4_g, bn4_b, bn4_rm, bn4_rv,
                                                   lin4_w, lin4_b,
                                                   bn5_g, bn5_b, bn5_rm, bn5_rv,
                                                   h4);

    // 3) graph convs + pool + heads
    graph_head_kernel<<<B, 128, 0, stream>>>(h4, ei, ew1, ew2,
                                             gc1_wrel, gc1_brel, gc1_wroot,
                                             bn6_g, bn6_b, bn6_rm, bn6_rv,
                                             gc2_wrel, gc2_brel, gc2_wroot,
                                             bn7_g, bn7_b, bn7_rm, bn7_rv,
                                             lin5_w, lin5_b,
                                             hm_w, hm_b, hb_w, hb_b, hd_w, hd_b,
                                             (float*)d_out, B, B * 60);
}

// Round 5
// 689.287 us; speedup vs baseline: 1.0788x; 1.0788x over previous
//
#include <hip/hip_runtime.h>
#include <math.h>

#define EPSBN 1e-5f

// ---------------------------------------------------------------------------
// Kernel 1: time-average. Output element o = mean(x[25o .. 25o+24]).
// Block = 256 threads, handles 256 outputs = 6400 contiguous input floats.
// Memory-bound: 389 MB read once, perfectly coalesced via LDS staging.
// At HBM roofline (verified: never appears above harness fills at 6.6 TB/s).
// ---------------------------------------------------------------------------
__global__ __launch_bounds__(256)
void mean25_kernel(const float* __restrict__ x, float* __restrict__ h1)
{
    __shared__ __align__(16) float s[6400];
    const int t = threadIdx.x;
    const float4* xv = (const float4*)(x + (size_t)blockIdx.x * 6400);
    float4* sv = (float4*)s;
#pragma unroll
    for (int i = 0; i < 6; ++i) sv[i * 256 + t] = xv[i * 256 + t];
    if (t < 64) sv[1536 + t] = xv[1536 + t];   // 1600 float4 total
    __syncthreads();
    const float* p = s + t * 25;               // stride 25, coprime to 32 banks
    float acc = 0.f;
#pragma unroll
    for (int k = 0; k < 25; ++k) acc += p[k];
    h1[(size_t)blockIdx.x * 256 + t] = acc * (1.0f / 25.0f);
}

// ---------------------------------------------------------------------------
// Kernel 2 (GEMM1): C[m,n] = BN_e( relu( sum_k A[m,k]*W[n,k] + bias[n] ) )
// BN per-electrode (e = m % 19). 64x64 tile, BK=32, 256 thr, 4x4/thread.
// LDS row stride padded 64 -> 68 floats (272 B): keeps ds_read_b128
// 16B-aligned while turning the 8-way staging-write bank conflict into 4-way.
// Fragment reads are broadcast/2-way (free). Near the f32 VALU floor.
// ---------------------------------------------------------------------------
__global__ __launch_bounds__(256)
void sgemm_relu_bnch(const float* __restrict__ A, const float* __restrict__ W,
                     const float* __restrict__ bias,
                     const float* __restrict__ bg, const float* __restrict__ bb,
                     const float* __restrict__ brm, const float* __restrict__ brv,
                     float* __restrict__ C, int M, int N, int K)
{
    __shared__ __align__(16) float As[32][68];
    __shared__ __align__(16) float Ws[32][68];
    const int tid = threadIdx.x;
    const int bm = blockIdx.y * 64;
    const int bn = blockIdx.x * 64;
    const int tm0 = (tid >> 4) * 4;        // 0..60
    const int tn0 = (tid & 15) * 4;        // 0..60
    const int r0 = tid >> 3;               // 0..31
    const int c0 = (tid & 7) * 4;          // 0,4,..,28

    float acc[4][4] = {};
    const float* A0 = A + (size_t)(bm + r0) * K + c0;
    const float* A1 = A + (size_t)(bm + r0 + 32) * K + c0;
    const float* W0 = W + (size_t)(bn + r0) * K + c0;
    const float* W1 = W + (size_t)(bn + r0 + 32) * K + c0;

    float4 a0 = *(const float4*)A0;
    float4 a1 = *(const float4*)A1;
    float4 w0 = *(const float4*)W0;
    float4 w1 = *(const float4*)W1;

    for (int k0 = 0; k0 < K; k0 += 32) {
        __syncthreads();                   // previous iter's readers done
        As[c0 + 0][r0] = a0.x; As[c0 + 1][r0] = a0.y;
        As[c0 + 2][r0] = a0.z; As[c0 + 3][r0] = a0.w;
        As[c0 + 0][r0 + 32] = a1.x; As[c0 + 1][r0 + 32] = a1.y;
        As[c0 + 2][r0 + 32] = a1.z; As[c0 + 3][r0 + 32] = a1.w;
        Ws[c0 + 0][r0] = w0.x; Ws[c0 + 1][r0] = w0.y;
        Ws[c0 + 2][r0] = w0.z; Ws[c0 + 3][r0] = w0.w;
        Ws[c0 + 0][r0 + 32] = w1.x; Ws[c0 + 1][r0 + 32] = w1.y;
        Ws[c0 + 2][r0 + 32] = w1.z; Ws[c0 + 3][r0 + 32] = w1.w;
        __syncthreads();
        if (k0 + 32 < K) {                 // prefetch next tile (hidden by FMAs)
            a0 = *(const float4*)(A0 + k0 + 32);
            a1 = *(const float4*)(A1 + k0 + 32);
            w0 = *(const float4*)(W0 + k0 + 32);
            w1 = *(const float4*)(W1 + k0 + 32);
        }
#pragma unroll
        for (int kk = 0; kk < 32; ++kk) {
            float4 a = *(const float4*)&As[kk][tm0];
            float4 b = *(const float4*)&Ws[kk][tn0];
            acc[0][0] += a.x * b.x; acc[0][1] += a.x * b.y;
            acc[0][2] += a.x * b.z; acc[0][3] += a.x * b.w;
            acc[1][0] += a.y * b.x; acc[1][1] += a.y * b.y;
            acc[1][2] += a.y * b.z; acc[1][3] += a.y * b.w;
            acc[2][0] += a.z * b.x; acc[2][1] += a.z * b.y;
            acc[2][2] += a.z * b.z; acc[2][3] += a.z * b.w;
            acc[3][0] += a.w * b.x; acc[3][1] += a.w * b.y;
            acc[3][2] += a.w * b.z; acc[3][3] += a.w * b.w;
        }
    }

    const float b0 = bias[bn + tn0 + 0];
    const float b1 = bias[bn + tn0 + 1];
    const float b2 = bias[bn + tn0 + 2];
    const float b3 = bias[bn + tn0 + 3];
#pragma unroll
    for (int i = 0; i < 4; ++i) {
        const int row = bm + tm0 + i;
        const int e = row % 19;
        const float scale = bg[e] * (1.0f / sqrtf(brv[e] + EPSBN));
        const float shift = bb[e] - brm[e] * scale;
        float4 o;
        o.x = fmaxf(acc[i][0] + b0, 0.f) * scale + shift;
        o.y = fmaxf(acc[i][1] + b1, 0.f) * scale + shift;
        o.z = fmaxf(acc[i][2] + b2, 0.f) * scale + shift;
        o.w = fmaxf(acc[i][3] + b3, 0.f) * scale + shift;
        *(float4*)(C + (size_t)row * N + bn + tn0) = o;
    }
}

// ---------------------------------------------------------------------------
// Kernel 3: fused lin3+BN4 then lin4+BN5 for a 32-row stripe.
// Phase 1: C1(32x128) = BN4(relu(h2[32x256] @ w3^T + b3))   (K=256, BK=32)
// Phase 2: h4(32x64)  = BN5(relu(C1 @ w4^T + b4))           (K=128, in-LDS)
// As/Ws strides 36/132 (4-way staging conflicts); lin4 staged transposed
// (W4T, conflict-free writes); phase 2 is an outer product over k with one
// contiguous conflict-free ds_read_b128 per k.  2 blocks/CU, 152 blocks.
// ---------------------------------------------------------------------------
__global__ __launch_bounds__(256)
void gemm23_fused(const float* __restrict__ h2,
                  const float* __restrict__ w3, const float* __restrict__ b3,
                  const float* __restrict__ g4, const float* __restrict__ bb4,
                  const float* __restrict__ rm4, const float* __restrict__ rv4,
                  const float* __restrict__ w4, const float* __restrict__ b4,
                  const float* __restrict__ g5, const float* __restrict__ bb5,
                  const float* __restrict__ rm5, const float* __restrict__ rv5,
                  float* __restrict__ h4out)
{
    __shared__ __align__(16) float As[32][36];    //  4.6 KB h2 tile, k-major
    __shared__ __align__(16) float Ws[32][132];   // 16.9 KB w3 tile, k-major
    __shared__ __align__(16) float C1[32][132];   // 16.9 KB phase-1 out
    __shared__ __align__(16) float W4T[128][68];  // 34.8 KB lin4, k-major rows

    const int t = threadIdx.x;
    const int bm = blockIdx.x * 32;

    // ---- phase 1: 32x128 GEMM, K=256 ----
    const int tm0 = (t >> 5) * 4;      // 0..28
    const int tn0 = (t & 31) * 4;      // 0..124
    const int ar = t >> 3;             // 0..31
    const int ac = (t & 7) * 4;        // 0,4,..,28

    float acc[4][4] = {};
    const float* Ap = h2 + (size_t)(bm + ar) * 256 + ac;
    float4 areg = *(const float4*)Ap;
    float4 wreg[4];
#pragma unroll
    for (int i = 0; i < 4; ++i)
        wreg[i] = *(const float4*)(w3 + (size_t)(ar + i * 32) * 256 + ac);

    for (int k0 = 0; k0 < 256; k0 += 32) {
        __syncthreads();
        As[ac + 0][ar] = areg.x; As[ac + 1][ar] = areg.y;
        As[ac + 2][ar] = areg.z; As[ac + 3][ar] = areg.w;
#pragma unroll
        for (int i = 0; i < 4; ++i) {
            const int row = ar + i * 32;
            Ws[ac + 0][row] = wreg[i].x; Ws[ac + 1][row] = wreg[i].y;
            Ws[ac + 2][row] = wreg[i].z; Ws[ac + 3][row] = wreg[i].w;
        }
        __syncthreads();
        if (k0 + 32 < 256) {
            areg = *(const float4*)(Ap + k0 + 32);
#pragma unroll
            for (int i = 0; i < 4; ++i)
                wreg[i] = *(const float4*)(w3 + (size_t)(ar + i * 32) * 256 + ac + k0 + 32);
        }
#pragma unroll
        for (int kk = 0; kk < 32; ++kk) {
            float4 a = *(const float4*)&As[kk][tm0];
            float4 b = *(const float4*)&Ws[kk][tn0];
            acc[0][0] += a.x * b.x; acc[0][1] += a.x * b.y;
            acc[0][2] += a.x * b.z; acc[0][3] += a.x * b.w;
            acc[1][0] += a.y * b.x; acc[1][1] += a.y * b.y;
            acc[1][2] += a.y * b.z; acc[1][3] += a.y * b.w;
            acc[2][0] += a.z * b.x; acc[2][1] += a.z * b.y;
            acc[2][2] += a.z * b.z; acc[2][3] += a.z * b.w;
            acc[3][0] += a.w * b.x; acc[3][1] += a.w * b.y;
            acc[3][2] += a.w * b.z; acc[3][3] += a.w * b.w;
        }
    }

    // epilogue 1 -> C1 (LDS)
    {
        const float c0 = b3[tn0 + 0], c1 = b3[tn0 + 1];
        const float c2 = b3[tn0 + 2], c3 = b3[tn0 + 3];
#pragma unroll
        for (int i = 0; i < 4; ++i) {
            const int e = (bm + tm0 + i) % 19;
            const float scale = g4[e] * (1.0f / sqrtf(rv4[e] + EPSBN));
            const float shift = bb4[e] - rm4[e] * scale;
            float4 o;
            o.x = fmaxf(acc[i][0] + c0, 0.f) * scale + shift;
            o.y = fmaxf(acc[i][1] + c1, 0.f) * scale + shift;
            o.z = fmaxf(acc[i][2] + c2, 0.f) * scale + shift;
            o.w = fmaxf(acc[i][3] + c3, 0.f) * scale + shift;
            *(float4*)&C1[tm0 + i][tn0] = o;
        }
    }

    // stage lin4 transposed (k-major rows, n-contiguous): conflict-free writes
    {
        const int ln = t & 63, wq = t >> 6;
#pragma unroll
        for (int ii = 0; ii < 8; ++ii) {
            const int c4 = wq + ii * 4;
            const float4 v = *(const float4*)(w4 + (size_t)ln * 128 + c4 * 4);
            W4T[c4 * 4 + 0][ln] = v.x;
            W4T[c4 * 4 + 1][ln] = v.y;
            W4T[c4 * 4 + 2][ln] = v.z;
            W4T[c4 * 4 + 3][ln] = v.w;
        }
    }
    __syncthreads();

    // ---- phase 2: 32x64 GEMM, K=128, outer product over k ----
    const int rm2 = (t >> 4) * 2;
    const int cn2 = (t & 15) * 4;
    float acc2[2][4] = {};
#pragma unroll 4
    for (int k = 0; k < 128; ++k) {
        const float a0 = C1[rm2 + 0][k];
        const float a1 = C1[rm2 + 1][k];
        const float4 w = *(const float4*)&W4T[k][cn2];
        acc2[0][0] += a0 * w.x; acc2[0][1] += a0 * w.y;
        acc2[0][2] += a0 * w.z; acc2[0][3] += a0 * w.w;
        acc2[1][0] += a1 * w.x; acc2[1][1] += a1 * w.y;
        acc2[1][2] += a1 * w.z; acc2[1][3] += a1 * w.w;
    }
    {
        const float c0 = b4[cn2 + 0], c1 = b4[cn2 + 1];
        const float c2 = b4[cn2 + 2], c3 = b4[cn2 + 3];
#pragma unroll
        for (int i = 0; i < 2; ++i) {
            const int row = bm + rm2 + i;
            const int e = row % 19;
            const float scale = g5[e] * (1.0f / sqrtf(rv5[e] + EPSBN));
            const float shift = bb5[e] - rm5[e] * scale;
            float4 o;
            o.x = fmaxf(acc2[i][0] + c0, 0.f) * scale + shift;
            o.y = fmaxf(acc2[i][1] + c1, 0.f) * scale + shift;
            o.z = fmaxf(acc2[i][2] + c2, 0.f) * scale + shift;
            o.w = fmaxf(acc2[i][3] + c3, 0.f) * scale + shift;
            *(float4*)(h4out + (size_t)row * 64 + cn2) = o;
        }
    }
}

// ---------------------------------------------------------------------------
// Kernel 4: fused GC1 + BN6 + GC2 + BN7 + maxpool + lin5 + 3 heads.
// One block (128 thr) per graph.
// ---------------------------------------------------------------------------
__global__ __launch_bounds__(128)
void graph_head_kernel(const float* __restrict__ h,
                       const int* __restrict__ ei,
                       const float* __restrict__ ew1, const float* __restrict__ ew2,
                       const float* __restrict__ wrel1, const float* __restrict__ brel1,
                       const float* __restrict__ wroot1,
                       const float* __restrict__ g6, const float* __restrict__ b6,
                       const float* __restrict__ rm6, const float* __restrict__ rv6,
                       const float* __restrict__ wrel2, const float* __restrict__ brel2,
                       const float* __restrict__ wroot2,
                       const float* __restrict__ g7, const float* __restrict__ b7,
                       const float* __restrict__ rm7, const float* __restrict__ rv7,
                       const float* __restrict__ lin5w, const float* __restrict__ lin5b,
                       const float* __restrict__ hmw, const float* __restrict__ hmb,
                       const float* __restrict__ hbw, const float* __restrict__ hbb,
                       const float* __restrict__ hdw, const float* __restrict__ hdb,
                       float* __restrict__ out, int nB, int nEdgeTot)
{
    __shared__ __align__(16) float sh[19 * 64];
    __shared__ __align__(16) float sagg[19 * 64];
    __shared__ __align__(16) float sh2[19 * 32];
    __shared__ __align__(16) float sagg2[19 * 32];
    __shared__ __align__(16) float sh3[19 * 32];
    __shared__ __align__(16) float swrel1[32 * 64];
    __shared__ __align__(16) float swroot1[32 * 64];
    __shared__ __align__(16) float swrel2[32 * 32];
    __shared__ __align__(16) float swroot2[32 * 32];
    __shared__ __align__(16) float slin5[32 * 32];
    __shared__ float sz[32], szz[32];
    __shared__ int ssrc[60], sdst[60];
    __shared__ float sew1[60], sew2[60];

    const int t = threadIdx.x;
    const int g = blockIdx.x;

    for (int i = t; i < 19 * 64; i += 128) { sh[i] = h[(size_t)g * 19 * 64 + i]; sagg[i] = 0.f; }
    for (int i = t; i < 19 * 32; i += 128) sagg2[i] = 0.f;
    for (int i = t; i < 2048; i += 128) { swrel1[i] = wrel1[i]; swroot1[i] = wroot1[i]; }
    for (int i = t; i < 1024; i += 128) { swrel2[i] = wrel2[i]; swroot2[i] = wroot2[i]; slin5[i] = lin5w[i]; }
    if (t < 60) {
        ssrc[t] = ei[g * 60 + t] - g * 19;
        sdst[t] = ei[nEdgeTot + g * 60 + t] - g * 19;
        sew1[t] = ew1[t];
        sew2[t] = ew2[t];
    }
    __syncthreads();

    if (t < 64) {
        for (int e = 0; e < 60; ++e)
            sagg[sdst[e] * 64 + t] += sew1[e] * sh[ssrc[e] * 64 + t];
    }
    __syncthreads();

    for (int idx = t; idx < 19 * 32; idx += 128) {
        const int n = idx >> 5, j = idx & 31;
        const float4* ag = (const float4*)&sagg[n * 64];
        const float4* hg = (const float4*)&sh[n * 64];
        const float4* wr = (const float4*)&swrel1[j * 64];
        const float4* wo = (const float4*)&swroot1[j * 64];
        float acc = brel1[j];
#pragma unroll
        for (int k = 0; k < 16; ++k) {
            float4 a = ag[k], w = wr[k], x = hg[k], u = wo[k];
            acc += a.x * w.x + a.y * w.y + a.z * w.z + a.w * w.w;
            acc += x.x * u.x + x.y * u.y + x.z * u.z + x.w * u.w;
        }
        float v = fmaxf(acc, 0.f);
        const float scale = g6[j] * (1.0f / sqrtf(rv6[j] + EPSBN));
        sh2[idx] = (v - rm6[j]) * scale + b6[j];
    }
    __syncthreads();

    if (t < 32) {
        for (int e = 0; e < 60; ++e)
            sagg2[sdst[e] * 32 + t] += sew2[e] * sh2[ssrc[e] * 32 + t];
    }
    __syncthreads();

    for (int idx = t; idx < 19 * 32; idx += 128) {
        const int n = idx >> 5, j = idx & 31;
        const float4* ag = (const float4*)&sagg2[n * 32];
        const float4* hg = (const float4*)&sh2[n * 32];
        const float4* wr = (const float4*)&swrel2[j * 32];
        const float4* wo = (const float4*)&swroot2[j * 32];
        float acc = brel2[j];
#pragma unroll
        for (int k = 0; k < 8; ++k) {
            float4 a = ag[k], w = wr[k], x = hg[k], u = wo[k];
            acc += a.x * w.x + a.y * w.y + a.z * w.z + a.w * w.w;
            acc += x.x * u.x + x.y * u.y + x.z * u.z + x.w * u.w;
        }
        float v = fmaxf(acc, 0.f);
        const float scale = g7[j] * (1.0f / sqrtf(rv7[j] + EPSBN));
        sh3[idx] = (v - rm7[j]) * scale + b7[j];
    }
    __syncthreads();

    if (t < 32) {
        float m = sh3[t];
        for (int n = 1; n < 19; ++n) m = fmaxf(m, sh3[n * 32 + t]);
        sz[t] = m;
    }
    __syncthreads();

    if (t < 32) {
        float acc = lin5b[t];
        const float4* zp = (const float4*)sz;
        const float4* wp = (const float4*)&slin5[t * 32];
#pragma unroll
        for (int k = 0; k < 8; ++k) {
            float4 z = zp[k], w = wp[k];
            acc += z.x * w.x + z.y * w.y + z.z * w.z + z.w * w.w;
        }
        szz[t] = fmaxf(acc, 0.f);
    }
    __syncthreads();

    if (t < 3) {
        float acc = hmb[t];
        for (int k = 0; k < 32; ++k) acc += szz[k] * hmw[t * 32 + k];
        out[g * 3 + t] = acc;
    } else if (t < 5) {
        const int j = t - 3;
        float acc = hbb[j];
        for (int k = 0; k < 32; ++k) acc += szz[k] * hbw[j * 32 + k];
        out[nB * 3 + g * 2 + j] = acc;
    } else if (t < 7) {
        const int j = t - 5;
        float acc = hdb[j];
        for (int k = 0; k < 32; ++k) acc += szz[k] * hdw[j * 32 + k];
        out[nB * 5 + g * 2 + j] = acc;
    }
}

// ---------------------------------------------------------------------------
extern "C" void kernel_launch(void* const* d_in, const int* in_sizes, int n_in,
                              void* d_out, int out_size, void* d_ws, size_t ws_size,
                              hipStream_t stream)
{
    const float* x       = (const float*)d_in[0];
    const int*   ei      = (const int*)d_in[1];
    const float* lin2_w  = (const float*)d_in[3];
    const float* lin2_b  = (const float*)d_in[4];
    const float* bn3_g   = (const float*)d_in[5];
    const float* bn3_b   = (const float*)d_in[6];
    const float* bn3_rm  = (const float*)d_in[7];
    const float* bn3_rv  = (const float*)d_in[8];
    const float* lin3_w  = (const float*)d_in[9];
    const float* lin3_b  = (const float*)d_in[10];
    const float* bn4_g   = (const float*)d_in[11];
    const float* bn4_b   = (const float*)d_in[12];
    const float* bn4_rm  = (const float*)d_in[13];
    const float* bn4_rv  = (const float*)d_in[14];
    const float* lin4_w  = (const float*)d_in[15];
    const float* lin4_b  = (const float*)d_in[16];
    const float* bn5_g   = (const float*)d_in[17];
    const float* bn5_b   = (const float*)d_in[18];
    const float* bn5_rm  = (const float*)d_in[19];
    const float* bn5_rv  = (const float*)d_in[20];
    const float* ew1     = (const float*)d_in[21];
    const float* gc1_wrel  = (const float*)d_in[22];
    const float* gc1_brel  = (const float*)d_in[23];
    const float* gc1_wroot = (const float*)d_in[24];
    const float* bn6_g   = (const float*)d_in[25];
    const float* bn6_b   = (const float*)d_in[26];
    const float* bn6_rm  = (const float*)d_in[27];
    const float* bn6_rv  = (const float*)d_in[28];
    const float* ew2     = (const float*)d_in[29];
    const float* gc2_wrel  = (const float*)d_in[30];
    const float* gc2_brel  = (const float*)d_in[31];
    const float* gc2_wroot = (const float*)d_in[32];
    const float* bn7_g   = (const float*)d_in[33];
    const float* bn7_b   = (const float*)d_in[34];
    const float* bn7_rm  = (const float*)d_in[35];
    const float* bn7_rv  = (const float*)d_in[36];
    const float* lin5_w  = (const float*)d_in[37];
    const float* lin5_b  = (const float*)d_in[38];
    const float* hm_w    = (const float*)d_in[39];
    const float* hm_b    = (const float*)d_in[40];
    const float* hb_w    = (const float*)d_in[41];
    const float* hb_b    = (const float*)d_in[42];
    const float* hd_w    = (const float*)d_in[43];
    const float* hd_b    = (const float*)d_in[44];

    const int n_nodes = in_sizes[0] / 20000;   // 4864
    const int B = n_nodes / 19;                // 256

    float* h1 = (float*)d_ws;                         // (n_nodes, 800)
    float* h2 = h1 + (size_t)n_nodes * 800;           // (n_nodes, 256)
    float* h4 = h2 + (size_t)n_nodes * 256;           // (n_nodes, 64)

    // 1) time-average
    mean25_kernel<<<(n_nodes * 800) / 256, 256, 0, stream>>>(x, h1);

    // 2) lin2 + relu + bn3
    dim3 g1(256 / 64, n_nodes / 64);
    sgemm_relu_bnch<<<g1, 256, 0, stream>>>(h1, lin2_w, lin2_b,
                                            bn3_g, bn3_b, bn3_rm, bn3_rv,
                                            h2, n_nodes, 256, 800);

    // 3) fused lin3+bn4 / lin4+bn5
    gemm23_fused<<<n_nodes / 32, 256, 0, stream>>>(h2,
                                                   lin3_w, lin3_b,
                                                   bn4_g, bn4_b, bn4_rm, bn4_rv,
                                                   lin4_w, lin4_b,
                                                   bn5_g, bn5_b, bn5_rm, bn5_rv,
                                                   h4);

    // 4) graph convs + pool + heads
    graph_head_kernel<<<B, 128, 0, stream>>>(h4, ei, ew1, ew2,
                                             gc1_wrel, gc1_brel, gc1_wroot,
                                             bn6_g, bn6_b, bn6_rm, bn6_rv,
                                             gc2_wrel, gc2_brel, gc2_wroot,
                                             bn7_g, bn7_b, bn7_rm, bn7_rv,
                                             lin5_w, lin5_b,
                                             hm_w, hm_b, hb_w, hb_b, hd_w, hd_b,
                                             (float*)d_out, B, B * 60);
}